// Round 2
// baseline (284.672 us; speedup 1.0000x reference)
//
#include <hip/hip_runtime.h>

#define DIM 64
#define NVOX (DIM * DIM * DIM)

// ---------------------------------------------------------------------------
// Lock-free union-find (ECL-CC style). Labels: flat voxel index for fg, -1 bg.
// Invariant: any value ever stored in L[x] is an ancestor of x with strictly
// smaller index -> stale (non-coherent L1) reads still see valid ancestors;
// atomicCAS is coherent ground truth, failed CAS returns strictly smaller
// value -> guaranteed termination even with maximally stale plain loads.
// ---------------------------------------------------------------------------

__device__ __forceinline__ int find_root_link(int* L, int v) {
    for (;;) {
        int p = L[v];
        if (p == v) return v;
        int gp = L[p];
        if (gp == p) return p;
        L[v] = gp;   // path-halving: writes an ancestor, races benign
        v = gp;
    }
}

__device__ __forceinline__ void unite(int* L, int a, int b) {
    int ra = find_root_link(L, a);
    int rb = find_root_link(L, b);
    while (ra != rb) {
        if (ra > rb) { int t = ra; ra = rb; rb = t; }
        int old = atomicCAS(&L[rb], rb, ra);
        if (old == rb) break;            // hooked rb -> ra
        rb = find_root_link(L, old);     // old is coherent, strictly < rb
        ra = find_root_link(L, ra);
    }
}

__global__ void init_labels(const float* __restrict__ pred,
                            const float* __restrict__ lab,
                            int* __restrict__ LP, int* __restrict__ LL) {
    int v = blockIdx.x * blockDim.x + threadIdx.x;
    if (v >= NVOX) return;
    LP[v] = (pred[v] > 0.0f) ? v : -1;
    LL[v] = (lab[v]  > 0.0f) ? v : -1;
}

__global__ void link_kernel(int* __restrict__ LP, int* __restrict__ LL) {
    int v = blockIdx.x * blockDim.x + threadIdx.x;
    if (v >= NVOX) return;
    int x = v & 63, y = (v >> 6) & 63, z = v >> 12;
    if (LP[v] >= 0) {   // fg flag: sign of L[x] is stable for the whole pass
        if (x < 63 && LP[v + 1]    >= 0) unite(LP, v, v + 1);
        if (y < 63 && LP[v + 64]   >= 0) unite(LP, v, v + 64);
        if (z < 63 && LP[v + 4096] >= 0) unite(LP, v, v + 4096);
    }
    if (LL[v] >= 0) {
        if (x < 63 && LL[v + 1]    >= 0) unite(LL, v, v + 1);
        if (y < 63 && LL[v + 64]   >= 0) unite(LL, v, v + 64);
        if (z < 63 && LL[v + 4096] >= 0) unite(LL, v, v + 4096);
    }
}

// Read-only chase + single own-entry store (no halving writes here, so a
// late racing write can never overwrite a final root with a non-root).
__global__ void compress_kernel(int* __restrict__ LP, int* __restrict__ LL) {
    int v = blockIdx.x * blockDim.x + threadIdx.x;
    if (v >= NVOX) return;
    int p = LP[v];
    if (p >= 0) { int q = LP[p]; while (q != p) { p = q; q = LP[p]; } LP[v] = p; }
    p = LL[v];
    if (p >= 0) { int q = LL[p]; while (q != p) { p = q; q = LL[p]; } LL[v] = p; }
}

// ---------------------------------------------------------------------------
// Exact component count of a 27-bit mask under adjacency table adj[27]
// (flood fill; total bit expansions <= popcount(mask) <= 27).
// ---------------------------------------------------------------------------
__device__ __forceinline__ int ncomp(unsigned mask, const unsigned* __restrict__ adj) {
    int n = 0;
    unsigned rem = mask;
    while (rem) {
        unsigned frontier = rem & (~rem + 1u);   // lowest set bit = seed
        unsigned comp = frontier;
        while (frontier) {
            unsigned grow = 0;
            do {
                int b = __ffs((int)frontier) - 1;
                frontier &= frontier - 1;
                grow |= adj[b];
            } while (frontier);
            frontier = grow & rem & ~comp;
            comp |= frontier;
        }
        rem &= ~comp;
        ++n;
    }
    return n;
}

__global__ void finalize_kernel(const float* __restrict__ pred,
                                const float* __restrict__ lab,
                                const int* __restrict__ LP,
                                const int* __restrict__ LL,
                                float* __restrict__ out) {
    __shared__ unsigned s_adj18[27];
    __shared__ unsigned s_adj26[27];
    __shared__ float s_part[4];
    int t = threadIdx.x;
    if (t < 27) {
        int z = t / 9, y = (t / 3) % 3, x = t % 3;
        unsigned a18 = 0, a26 = 0;
        for (int j = 0; j < 27; ++j) {
            if (j == t) continue;
            int dz = (j / 9) - z;       if (dz < 0) dz = -dz;
            int dy = ((j / 3) % 3) - y; if (dy < 0) dy = -dy;
            int dx = (j % 3) - x;       if (dx < 0) dx = -dx;
            // Window-cell adjacency: offset must be a valid member of the
            // offset set, i.e. EVERY component in {-1,0,1} (Chebyshev <= 1).
            if (dz <= 1 && dy <= 1 && dx <= 1) {
                a26 |= 1u << j;                                    // 26-conn
                if (!(dz == 1 && dy == 1 && dx == 1)) a18 |= 1u << j; // 18-conn: no corners
            }
        }
        s_adj18[t] = a18;
        s_adj26[t] = a26;
    }
    __syncthreads();

    int v = blockIdx.x * blockDim.x + t;   // grid is exact: NVOX/256 blocks
    int x = v & 63, y = (v >> 6) & 63, z = v >> 12;

    int idx27[27];
#pragma unroll
    for (int k = 0; k < 27; ++k) {
        int dz = k / 9 - 1, dy = (k / 3) % 3 - 1, dx = k % 3 - 1;
        int zz = z + dz; zz = zz < 0 ? 0 : (zz > 63 ? 63 : zz);  // edge pad
        int yy = y + dy; yy = yy < 0 ? 0 : (yy > 63 ? 63 : yy);
        int xx = x + dx; xx = xx < 0 ? 0 : (xx > 63 ? 63 : xx);
        idx27[k] = (zz << 12) | (yy << 6) | xx;
    }

    bool nsP = false, nsL = false;
    int c = LP[v];
    if (c >= 0) {
        unsigned m1 = 0, m2 = 0;
#pragma unroll
        for (int k = 0; k < 27; ++k) {
            int w = LP[idx27[k]];
            m1 |= (unsigned)(w != c) << k;
            m2 |= (unsigned)(w == c) << k;
        }
        m2 &= ~(1u << 13);  // drop center
        nsP = (ncomp(m1, s_adj18) != 1) || (ncomp(m2, s_adj26) != 1);
    }
    c = LL[v];
    if (c >= 0) {
        unsigned m1 = 0, m2 = 0;
#pragma unroll
        for (int k = 0; k < 27; ++k) {
            int w = LL[idx27[k]];
            m1 |= (unsigned)(w != c) << k;
            m2 |= (unsigned)(w == c) << k;
        }
        m2 &= ~(1u << 13);
        nsL = (ncomp(m1, s_adj18) != 1) || (ncomp(m2, s_adj26) != 1);
    }

    float p = pred[v], l = lab[v];
    float cost = fmaxf(p, 0.0f) - p * l + log1pf(__expf(-fabsf(p)));
    float w = (nsP || nsL) ? 5.0f : 1.0f;
    float contrib = w * cost;

#pragma unroll
    for (int off = 32; off > 0; off >>= 1)
        contrib += __shfl_down(contrib, off, 64);
    if ((t & 63) == 0) s_part[t >> 6] = contrib;
    __syncthreads();
    if (t == 0) {
        float s = s_part[0] + s_part[1] + s_part[2] + s_part[3];
        atomicAdd(out, s * (1.0f / (float)NVOX));
    }
}

extern "C" void kernel_launch(void* const* d_in, const int* in_sizes, int n_in,
                              void* d_out, int out_size, void* d_ws, size_t ws_size,
                              hipStream_t stream) {
    const float* pred = (const float*)d_in[0];   // 'prediction'
    const float* lab  = (const float*)d_in[1];   // 'label'
    float* out = (float*)d_out;

    int* LP = (int*)d_ws;          // NVOX ints
    int* LL = LP + NVOX;           // NVOX ints  (2 MiB total)

    hipMemsetAsync(d_out, 0, sizeof(float), stream);   // async memset: capturable

    dim3 blk(256), grd(NVOX / 256);
    hipLaunchKernelGGL(init_labels,     grd, blk, 0, stream, pred, lab, LP, LL);
    hipLaunchKernelGGL(link_kernel,     grd, blk, 0, stream, LP, LL);
    hipLaunchKernelGGL(compress_kernel, grd, blk, 0, stream, LP, LL);
    hipLaunchKernelGGL(finalize_kernel, grd, blk, 0, stream, pred, lab, LP, LL, out);
}

// Round 4
// 128.089 us; speedup vs baseline: 2.2224x; 2.2224x over previous
//
#include <hip/hip_runtime.h>

#define DIM 64
#define NVOX (DIM * DIM * DIM)

// ---------------------------------------------------------------------------
// Lock-free union-find (ECL-CC style), works on global OR LDS int arrays.
// Invariant: every stored parent is a strictly-smaller-index ancestor ->
// stale reads still see valid ancestors; atomicCAS is coherent ground truth;
// failed CAS returns a strictly smaller value -> guaranteed termination.
// ---------------------------------------------------------------------------
__device__ __forceinline__ int find_root_link(int* L, int v) {
    for (;;) {
        int p = L[v];
        if (p == v) return v;
        int gp = L[p];
        if (gp == p) return p;
        L[v] = gp;   // path-halving: writes an ancestor, races benign
        v = gp;
    }
}

__device__ __forceinline__ void unite(int* L, int a, int b) {
    int ra = find_root_link(L, a);
    int rb = find_root_link(L, b);
    while (ra != rb) {
        if (ra > rb) { int t = ra; ra = rb; rb = t; }
        int old = atomicCAS(&L[rb], rb, ra);
        if (old == rb) break;            // hooked rb -> ra
        rb = find_root_link(L, old);     // old coherent, strictly < rb
        ra = find_root_link(L, ra);
    }
}

// ---------------------------------------------------------------------------
// Phase 1: per-tile CCL in LDS (tile 16x8x4 = 512 voxels), write global
// label = global index of tile-local root (monotone map keeps parent<child).
// blockIdx.y selects field (0=pred, 1=label). Replaces init_labels too.
// ---------------------------------------------------------------------------
__global__ void local_ccl(const float* __restrict__ pred,
                          const float* __restrict__ lab,
                          int* __restrict__ LP, int* __restrict__ LL) {
    __shared__ int s_lab[512];
    int t = threadIdx.x;
    int b = blockIdx.x;                         // 512 tiles: 4 x 8 x 16
    int tx = b & 3, ty = (b >> 2) & 7, tz = b >> 5;
    int lx = t & 15, ly = (t >> 4) & 7, lz = t >> 7;
    int x = (tx << 4) | lx, y = (ty << 3) | ly, z = (tz << 2) | lz;
    int v = (z << 12) | (y << 6) | x;

    const float* src = blockIdx.y ? lab : pred;
    int* Lg = blockIdx.y ? LL : LP;

    bool fg = src[v] > 0.0f;
    s_lab[t] = fg ? t : -1;
    __syncthreads();

    if (fg) {   // internal 6-conn edges only (LDS atomics, CU-local)
        if (lx < 15 && s_lab[t + 1]   >= 0) unite(s_lab, t, t + 1);
        if (ly < 7  && s_lab[t + 16]  >= 0) unite(s_lab, t, t + 16);
        if (lz < 3  && s_lab[t + 128] >= 0) unite(s_lab, t, t + 128);
    }
    __syncthreads();

    int g = -1;
    if (fg) {
        int p = s_lab[t];
        while (s_lab[p] != p) p = s_lab[p];     // read-only chase
        int rx = (tx << 4) | (p & 15);
        int ry = (ty << 3) | ((p >> 4) & 7);
        int rz = (tz << 2) | (p >> 7);
        g = (rz << 12) | (ry << 6) | rx;        // g <= v (monotone map)
    }
    Lg[v] = g;
}

// ---------------------------------------------------------------------------
// Phase 2: global unites across tile faces only (~115k edges/field vs 786k).
// ---------------------------------------------------------------------------
__global__ void boundary_link(int* __restrict__ LP, int* __restrict__ LL) {
    int v = blockIdx.x * blockDim.x + threadIdx.x;
    int x = v & 63, y = (v >> 6) & 63, z = v >> 12;
    bool bx = ((x & 15) == 15) && (x != 63);
    bool by = ((y & 7)  == 7)  && (y != 63);
    bool bz = ((z & 3)  == 3)  && (z != 63);
    if (!(bx | by | bz)) return;
    if (LP[v] >= 0) {
        if (bx && LP[v + 1]    >= 0) unite(LP, v, v + 1);
        if (by && LP[v + 64]   >= 0) unite(LP, v, v + 64);
        if (bz && LP[v + 4096] >= 0) unite(LP, v, v + 4096);
    }
    if (LL[v] >= 0) {
        if (bx && LL[v + 1]    >= 0) unite(LL, v, v + 1);
        if (by && LL[v + 64]   >= 0) unite(LL, v, v + 64);
        if (bz && LL[v + 4096] >= 0) unite(LL, v, v + 4096);
    }
}

// Read-only chase + single own-entry store.
__global__ void compress_kernel(int* __restrict__ LP, int* __restrict__ LL) {
    int v = blockIdx.x * blockDim.x + threadIdx.x;
    int p = LP[v];
    if (p >= 0) { int q = LP[p]; while (q != p) { p = q; q = LP[p]; } LP[v] = p; }
    p = LL[v];
    if (p >= 0) { int q = LL[p]; while (q != p) { p = q; q = LL[p]; } LL[v] = p; }
}

// ---------------------------------------------------------------------------
// 27-bit 3x3x3 mask connectivity via branch-free separable dilation.
// Bit index = z*9 + y*3 + x.
// ---------------------------------------------------------------------------
#define MX_L 0x6DB6DB6u   // result x in {1,2}
#define MX_R 0x36DB6DBu   // result x in {0,1}
#define MY_L 0x7E3F1F8u   // result y in {1,2}
#define MY_R 0x0FC7E3Fu   // result y in {0,1}
#define M27  0x7FFFFFFu

__device__ __forceinline__ unsigned dil26(unsigned m) {
    m |= ((m << 1) & MX_L) | ((m >> 1) & MX_R);
    m |= ((m << 3) & MY_L) | ((m >> 3) & MY_R);
    m |= ((m << 9) & M27)  | (m >> 9);
    return m;
}
__device__ __forceinline__ unsigned dil18(unsigned m) {
    unsigned ax = m | ((m << 1) & MX_L) | ((m >> 1) & MX_R);    // Dx
    unsigned ay = m | ((m << 3) & MY_L) | ((m >> 3) & MY_R);    // Dy
    unsigned dxy = ax | ((ax << 3) & MY_L) | ((ax >> 3) & MY_R);      // DyDx
    unsigned dxz = ax | ((ax << 9) & M27)  | (ax >> 9);               // DzDx
    unsigned dyz = ay | ((ay << 9) & M27)  | (ay >> 9);               // DzDy
    return dxy | dxz | dyz;   // all offsets with >=1 zero component
}

// true iff mask is nonempty and a single connected component
__device__ __forceinline__ bool single18(unsigned m) {
    if (!m) return false;
    unsigned c = m & (~m + 1u);
    for (;;) {
        unsigned n = dil18(c) & m;
        if (n == m) return true;
        if (n == c) return false;
        c = n;
    }
}
__device__ __forceinline__ bool single26(unsigned m) {
    if (!m) return false;
    unsigned c = m & (~m + 1u);
    for (;;) {
        unsigned n = dil26(c) & m;
        if (n == m) return true;
        if (n == c) return false;
        c = n;
    }
}

// ---------------------------------------------------------------------------
// Phase 4: non-simple maps + weighted BCE + mean. LDS halo 10x10x6 per field.
// Tile 8x8x4, block 256, grid 1024.
// ---------------------------------------------------------------------------
#define HV 600   // 10*10*6

__global__ void finalize_kernel(const float* __restrict__ pred,
                                const float* __restrict__ lab,
                                const int* __restrict__ LP,
                                const int* __restrict__ LL,
                                float* __restrict__ out) {
    __shared__ int sP[HV], sL[HV];
    __shared__ float s_part[4];
    int t = threadIdx.x;
    int b = blockIdx.x;                          // 8 x 8 x 16 tiles
    int tx = b & 7, ty = (b >> 3) & 7, tz = b >> 6;
    int x0 = tx << 3, y0 = ty << 3, z0 = tz << 2;

    for (int i = t; i < HV; i += 256) {
        int hx = i % 10, r = i / 10, hy = r % 10, hz = r / 10;
        int gx = x0 + hx - 1; gx = gx < 0 ? 0 : (gx > 63 ? 63 : gx);  // edge pad
        int gy = y0 + hy - 1; gy = gy < 0 ? 0 : (gy > 63 ? 63 : gy);
        int gz = z0 + hz - 1; gz = gz < 0 ? 0 : (gz > 63 ? 63 : gz);
        int gv = (gz << 12) | (gy << 6) | gx;
        sP[i] = LP[gv];
        sL[i] = LL[gv];
    }
    __syncthreads();

    // tile 8x8x4: lx = bits[0:3), ly = bits[3:6), lz = bits[6:8)  (FIXED: was t>>5)
    int lx = t & 7, ly = (t >> 3) & 7, lz = t >> 6;
    int x = x0 | lx, y = y0 | ly, z = z0 | lz;
    int v = (z << 12) | (y << 6) | x;
    int base = lz * 100 + ly * 10 + lx;          // halo idx of (-1,-1,-1) corner

    bool nsP = false, nsL = false;
    {
        int c = sP[base + 111];                  // center
        if (c >= 0) {
            unsigned m1 = 0, m2 = 0; int k = 0;
#pragma unroll
            for (int kz = 0; kz < 3; ++kz)
#pragma unroll
                for (int ky = 0; ky < 3; ++ky)
#pragma unroll
                    for (int kx = 0; kx < 3; ++kx, ++k) {
                        int w = sP[base + kz * 100 + ky * 10 + kx];
                        m1 |= (unsigned)(w != c) << k;
                        m2 |= (unsigned)(w == c) << k;
                    }
            m2 &= ~(1u << 13);                   // drop center
            nsP = !(single18(m1) && single26(m2));
        }
    }
    {
        int c = sL[base + 111];
        if (c >= 0) {
            unsigned m1 = 0, m2 = 0; int k = 0;
#pragma unroll
            for (int kz = 0; kz < 3; ++kz)
#pragma unroll
                for (int ky = 0; ky < 3; ++ky)
#pragma unroll
                    for (int kx = 0; kx < 3; ++kx, ++k) {
                        int w = sL[base + kz * 100 + ky * 10 + kx];
                        m1 |= (unsigned)(w != c) << k;
                        m2 |= (unsigned)(w == c) << k;
                    }
            m2 &= ~(1u << 13);
            nsL = !(single18(m1) && single26(m2));
        }
    }

    float p = pred[v], l = lab[v];
    float cost = fmaxf(p, 0.0f) - p * l + log1pf(__expf(-fabsf(p)));
    float w = (nsP || nsL) ? 5.0f : 1.0f;
    float contrib = w * cost;

#pragma unroll
    for (int off = 32; off > 0; off >>= 1)
        contrib += __shfl_down(contrib, off, 64);
    if ((t & 63) == 0) s_part[t >> 6] = contrib;
    __syncthreads();
    if (t == 0) {
        float s = s_part[0] + s_part[1] + s_part[2] + s_part[3];
        atomicAdd(out, s * (1.0f / (float)NVOX));
    }
}

extern "C" void kernel_launch(void* const* d_in, const int* in_sizes, int n_in,
                              void* d_out, int out_size, void* d_ws, size_t ws_size,
                              hipStream_t stream) {
    const float* pred = (const float*)d_in[0];   // 'prediction'
    const float* lab  = (const float*)d_in[1];   // 'label'
    float* out = (float*)d_out;

    int* LP = (int*)d_ws;          // NVOX ints
    int* LL = LP + NVOX;           // NVOX ints  (2 MiB total)

    hipMemsetAsync(d_out, 0, sizeof(float), stream);

    hipLaunchKernelGGL(local_ccl, dim3(512, 2), dim3(512), 0, stream,
                       pred, lab, LP, LL);
    hipLaunchKernelGGL(boundary_link, dim3(NVOX / 256), dim3(256), 0, stream,
                       LP, LL);
    hipLaunchKernelGGL(compress_kernel, dim3(NVOX / 256), dim3(256), 0, stream,
                       LP, LL);
    hipLaunchKernelGGL(finalize_kernel, dim3(NVOX / 256), dim3(256), 0, stream,
                       pred, lab, LP, LL, out);
}

// Round 5
// 116.043 us; speedup vs baseline: 2.4532x; 1.1038x over previous
//
#include <hip/hip_runtime.h>

#define DIM 64
#define NVOX (DIM * DIM * DIM)

// ---------------------------------------------------------------------------
// Lock-free union-find (ECL-CC style), works on global OR LDS int arrays.
// Invariant: every stored parent is a strictly-smaller-index ancestor ->
// stale reads still see valid ancestors; atomicCAS is coherent ground truth;
// failed CAS returns a strictly smaller value -> guaranteed termination.
// ---------------------------------------------------------------------------
__device__ __forceinline__ int find_root_link(int* L, int v) {
    for (;;) {
        int p = L[v];
        if (p == v) return v;
        int gp = L[p];
        if (gp == p) return p;
        L[v] = gp;   // path-halving: writes an ancestor, races benign
        v = gp;
    }
}

__device__ __forceinline__ void unite(int* L, int a, int b) {
    int ra = find_root_link(L, a);
    int rb = find_root_link(L, b);
    while (ra != rb) {
        if (ra > rb) { int t = ra; ra = rb; rb = t; }
        int old = atomicCAS(&L[rb], rb, ra);
        if (old == rb) break;            // hooked rb -> ra
        rb = find_root_link(L, old);     // old coherent, strictly < rb
        ra = find_root_link(L, ra);
    }
}

// ---------------------------------------------------------------------------
// Phase 1: per-tile CCL in LDS. Tile 16x16x8 = 2048 voxels, 256 threads
// (8 voxels/thread), grid (128 tiles, 2 fields) = 256 blocks -> full machine.
// Writes global label = global index of tile-local root (local->global index
// map is monotone, so parent <= child is preserved globally).
// ---------------------------------------------------------------------------
__global__ void local_ccl(const float* __restrict__ pred,
                          const float* __restrict__ lab,
                          int* __restrict__ LP, int* __restrict__ LL) {
    __shared__ int s_lab[2048];
    int t = threadIdx.x;
    int b = blockIdx.x;                         // 128 tiles: 4 x 4 x 8
    int tx = b & 3, ty = (b >> 2) & 3, tz = b >> 4;
    int X0 = tx << 4, Y0 = ty << 4, Z0 = tz << 3;

    const float* src = blockIdx.y ? lab : pred;
    int* Lg = blockIdx.y ? LL : LP;

    bool fg[8];
    int vv[8];
#pragma unroll
    for (int i = 0; i < 8; ++i) {
        int l = t + (i << 8);                   // lx=l&15, ly=(l>>4)&15, lz=l>>8
        int v = ((Z0 + (l >> 8)) << 12) | ((Y0 + ((l >> 4) & 15)) << 6)
              | (X0 + (l & 15));
        vv[i] = v;
        fg[i] = src[v] > 0.0f;
        s_lab[l] = fg[i] ? l : -1;
    }
    __syncthreads();

#pragma unroll
    for (int i = 0; i < 8; ++i) {
        if (!fg[i]) continue;
        int l = t + (i << 8);
        int lx = l & 15, ly = (l >> 4) & 15, lz = l >> 8;
        if (lx < 15 && s_lab[l + 1]   >= 0) unite(s_lab, l, l + 1);
        if (ly < 15 && s_lab[l + 16]  >= 0) unite(s_lab, l, l + 16);
        if (lz < 7  && s_lab[l + 256] >= 0) unite(s_lab, l, l + 256);
    }
    __syncthreads();

#pragma unroll
    for (int i = 0; i < 8; ++i) {
        int g = -1;
        if (fg[i]) {
            int p = s_lab[t + (i << 8)];
            while (s_lab[p] != p) p = s_lab[p];  // read-only chase
            g = ((Z0 + (p >> 8)) << 12) | ((Y0 + ((p >> 4) & 15)) << 6)
              | (X0 + (p & 15));
        }
        Lg[vv[i]] = g;
    }
}

// ---------------------------------------------------------------------------
// Phase 2: compact cross-tile edge list. Per field: x-planes {15,31,47},
// y-planes {15,31,47}, z-planes {7,...,55} -> (3+3+7)*4096 = 53248 edges.
// Both fields: 106496 threads = 416 blocks x 256.
// ---------------------------------------------------------------------------
#define EPF 53248

__global__ void boundary_link(int* __restrict__ LP, int* __restrict__ LL) {
    int e = blockIdx.x * blockDim.x + threadIdx.x;
    int f = e >= EPF;
    int r = f ? e - EPF : e;
    int* L = f ? LL : LP;
    int v, n;
    if (r < 12288) {                             // x-faces
        int plane = 15 + ((r >> 12) << 4);
        int ij = r & 4095;                       // y = ij&63, z = ij>>6
        v = ((ij >> 6) << 12) | ((ij & 63) << 6) | plane;
        n = v + 1;
    } else if (r < 24576) {                      // y-faces
        int r2 = r - 12288;
        int plane = 15 + ((r2 >> 12) << 4);
        int ij = r2 & 4095;                      // x = ij&63, z = ij>>6
        v = ((ij >> 6) << 12) | (plane << 6) | (ij & 63);
        n = v + 64;
    } else {                                     // z-faces
        int r3 = r - 24576;
        int plane = 7 + ((r3 >> 12) << 3);
        int ij = r3 & 4095;                      // x = ij&63, y = ij>>6
        v = (plane << 12) | ((ij >> 6) << 6) | (ij & 63);
        n = v + 4096;
    }
    if (L[v] >= 0 && L[n] >= 0) unite(L, v, n);
}

// ---------------------------------------------------------------------------
// 27-bit 3x3x3 mask connectivity via branch-free separable dilation.
// Bit index = z*9 + y*3 + x.
// ---------------------------------------------------------------------------
#define MX_L 0x6DB6DB6u   // result x in {1,2}
#define MX_R 0x36DB6DBu   // result x in {0,1}
#define MY_L 0x7E3F1F8u   // result y in {1,2}
#define MY_R 0x0FC7E3Fu   // result y in {0,1}
#define M27  0x7FFFFFFu

__device__ __forceinline__ unsigned dil26(unsigned m) {
    m |= ((m << 1) & MX_L) | ((m >> 1) & MX_R);
    m |= ((m << 3) & MY_L) | ((m >> 3) & MY_R);
    m |= ((m << 9) & M27)  | (m >> 9);
    return m;
}
__device__ __forceinline__ unsigned dil18(unsigned m) {
    unsigned ax = m | ((m << 1) & MX_L) | ((m >> 1) & MX_R);    // Dx
    unsigned ay = m | ((m << 3) & MY_L) | ((m >> 3) & MY_R);    // Dy
    unsigned dxy = ax | ((ax << 3) & MY_L) | ((ax >> 3) & MY_R);      // DyDx
    unsigned dxz = ax | ((ax << 9) & M27)  | (ax >> 9);               // DzDx
    unsigned dyz = ay | ((ay << 9) & M27)  | (ay >> 9);               // DzDy
    return dxy | dxz | dyz;   // all offsets with >=1 zero component
}

// true iff mask is nonempty and a single connected component
__device__ __forceinline__ bool single18(unsigned m) {
    if (!m) return false;
    unsigned c = m & (~m + 1u);
    for (;;) {
        unsigned n = dil18(c) & m;
        if (n == m) return true;
        if (n == c) return false;
        c = n;
    }
}
__device__ __forceinline__ bool single26(unsigned m) {
    if (!m) return false;
    unsigned c = m & (~m + 1u);
    for (;;) {
        unsigned n = dil26(c) & m;
        if (n == m) return true;
        if (n == c) return false;
        c = n;
    }
}

// ---------------------------------------------------------------------------
// Phase 3: non-simple maps + weighted BCE + mean. Halo loads chase labels to
// their final roots (replaces the former compress dispatch; read-only, exact).
// Tile 8x8x4, block 256, grid 1024. Halo 10x10x6 per field.
// ---------------------------------------------------------------------------
#define HV 600   // 10*10*6

__global__ void finalize_kernel(const float* __restrict__ pred,
                                const float* __restrict__ lab,
                                const int* __restrict__ LP,
                                const int* __restrict__ LL,
                                float* __restrict__ out) {
    __shared__ int sP[HV], sL[HV];
    __shared__ float s_part[4];
    int t = threadIdx.x;
    int b = blockIdx.x;                          // 8 x 8 x 16 tiles
    int tx = b & 7, ty = (b >> 3) & 7, tz = b >> 6;
    int x0 = tx << 3, y0 = ty << 3, z0 = tz << 2;

    for (int i = t; i < HV; i += 256) {
        int hx = i % 10, r = i / 10, hy = r % 10, hz = r / 10;
        int gx = x0 + hx - 1; gx = gx < 0 ? 0 : (gx > 63 ? 63 : gx);  // edge pad
        int gy = y0 + hy - 1; gy = gy < 0 ? 0 : (gy > 63 ? 63 : gy);
        int gz = z0 + hz - 1; gz = gz < 0 ? 0 : (gz > 63 ? 63 : gz);
        int gv = (gz << 12) | (gy << 6) | gx;
        int p = LP[gv];
        if (p >= 0) { int q = LP[p]; while (q != p) { p = q; q = LP[p]; } }
        sP[i] = p;
        p = LL[gv];
        if (p >= 0) { int q = LL[p]; while (q != p) { p = q; q = LL[p]; } }
        sL[i] = p;
    }
    __syncthreads();

    // tile 8x8x4: lx = bits[0:3), ly = bits[3:6), lz = bits[6:8)
    int lx = t & 7, ly = (t >> 3) & 7, lz = t >> 6;
    int x = x0 | lx, y = y0 | ly, z = z0 | lz;
    int v = (z << 12) | (y << 6) | x;
    int base = lz * 100 + ly * 10 + lx;          // halo idx of (-1,-1,-1) corner

    bool nsP = false, nsL = false;
    {
        int c = sP[base + 111];                  // center
        if (c >= 0) {
            unsigned m1 = 0, m2 = 0; int k = 0;
#pragma unroll
            for (int kz = 0; kz < 3; ++kz)
#pragma unroll
                for (int ky = 0; ky < 3; ++ky)
#pragma unroll
                    for (int kx = 0; kx < 3; ++kx, ++k) {
                        int w = sP[base + kz * 100 + ky * 10 + kx];
                        m1 |= (unsigned)(w != c) << k;
                        m2 |= (unsigned)(w == c) << k;
                    }
            m2 &= ~(1u << 13);                   // drop center
            nsP = !(single18(m1) && single26(m2));
        }
    }
    {
        int c = sL[base + 111];
        if (c >= 0) {
            unsigned m1 = 0, m2 = 0; int k = 0;
#pragma unroll
            for (int kz = 0; kz < 3; ++kz)
#pragma unroll
                for (int ky = 0; ky < 3; ++ky)
#pragma unroll
                    for (int kx = 0; kx < 3; ++kx, ++k) {
                        int w = sL[base + kz * 100 + ky * 10 + kx];
                        m1 |= (unsigned)(w != c) << k;
                        m2 |= (unsigned)(w == c) << k;
                    }
            m2 &= ~(1u << 13);
            nsL = !(single18(m1) && single26(m2));
        }
    }

    float p = pred[v], l = lab[v];
    float cost = fmaxf(p, 0.0f) - p * l + log1pf(__expf(-fabsf(p)));
    float w = (nsP || nsL) ? 5.0f : 1.0f;
    float contrib = w * cost;

#pragma unroll
    for (int off = 32; off > 0; off >>= 1)
        contrib += __shfl_down(contrib, off, 64);
    if ((t & 63) == 0) s_part[t >> 6] = contrib;
    __syncthreads();
    if (t == 0) {
        float s = s_part[0] + s_part[1] + s_part[2] + s_part[3];
        atomicAdd(out, s * (1.0f / (float)NVOX));
    }
}

extern "C" void kernel_launch(void* const* d_in, const int* in_sizes, int n_in,
                              void* d_out, int out_size, void* d_ws, size_t ws_size,
                              hipStream_t stream) {
    const float* pred = (const float*)d_in[0];   // 'prediction'
    const float* lab  = (const float*)d_in[1];   // 'label'
    float* out = (float*)d_out;

    int* LP = (int*)d_ws;          // NVOX ints
    int* LL = LP + NVOX;           // NVOX ints  (2 MiB total)

    hipMemsetAsync(d_out, 0, sizeof(float), stream);

    hipLaunchKernelGGL(local_ccl, dim3(128, 2), dim3(256), 0, stream,
                       pred, lab, LP, LL);
    hipLaunchKernelGGL(boundary_link, dim3(2 * EPF / 256), dim3(256), 0, stream,
                       LP, LL);
    hipLaunchKernelGGL(finalize_kernel, dim3(NVOX / 256), dim3(256), 0, stream,
                       pred, lab, LP, LL, out);
}